// Round 9
// baseline (506.079 us; speedup 1.0000x reference)
//
#include <hip/hip_runtime.h>
#include <stdint.h>

#define BATCH 8
#define NCH 256
#define BCH 128
#define KFR 32000
#define TOUT 256008
#define KT 32                    // frames per block (one tile per block)
#define NCHUNK (KFR / KT)        // 1000
#define XTW 128                  // words per xt row (256 bf16 n-channels)
#define LOC_FLOATS (8 * KT + 8)  // 264

typedef __attribute__((ext_vector_type(8))) short bf16x8;
typedef __attribute__((ext_vector_type(4))) float f32x4;
typedef __attribute__((ext_vector_type(4))) unsigned int u32x4;

__device__ __forceinline__ unsigned short f32_to_bf16(float f) {
    unsigned int u = __builtin_bit_cast(unsigned int, f);
    u += 0x7FFFu + ((u >> 16) & 1u);   // round-to-nearest-even
    return (unsigned short)(u >> 16);
}
__device__ __forceinline__ unsigned int pack2(float a, float b) {
    return (unsigned int)f32_to_bf16(a) | ((unsigned int)f32_to_bf16(b) << 16);
}
// 4 strided scalar loads (stride KFR) into an ext_vector (SROA-safe)
__device__ __forceinline__ f32x4 mload(const float* p) {
    f32x4 v;
    v[0] = p[0];
    v[1] = p[(size_t)KFR];
    v[2] = p[(size_t)2 * KFR];
    v[3] = p[(size_t)3 * KFR];
    return v;
}
// MFMA B-fragment (8 consecutive b-rows at column f) straight from global fp32
__device__ __forceinline__ bf16x8 bfrag8(const float* p) {
    u32x4 t;
    t[0] = pack2(p[0],              p[(size_t)KFR]);
    t[1] = pack2(p[(size_t)2 * KFR], p[(size_t)3 * KFR]);
    t[2] = pack2(p[(size_t)4 * KFR], p[(size_t)5 * KFR]);
    t[3] = pack2(p[(size_t)6 * KFR], p[(size_t)7 * KFR]);
    return __builtin_bit_cast(bf16x8, t);
}

__global__ void convert_weights(const float* __restrict__ Wm,
                                const float* __restrict__ Wb,
                                unsigned short* __restrict__ wbf) {
    int i = blockIdx.x * 256 + threadIdx.x;
    if (i < NCH * BCH) wbf[i] = f32_to_bf16(Wm[i]);
    if (i < 16 * NCH)  wbf[NCH * BCH + i] = f32_to_bf16(Wb[i]);
}

__global__ __launch_bounds__(256, 8)
void fused_decoder(const float* __restrict__ mix,
                   const float* __restrict__ est,
                   const unsigned short* __restrict__ wbf,
                   float* __restrict__ out) {
    __shared__ __align__(16) unsigned int xtd[32 * XTW];   // x bf16 [32 f][256 n], swizzled
    __shared__ __align__(16) float locout[LOC_FLOATS];     // per-chunk OLA accumulator

    const int tid = threadIdx.x;
    const int lane = tid & 63;
    const int wv = tid >> 6;
    const int l15 = lane & 15;
    const int lq = lane >> 4;

    const int bid = blockIdx.x;
    const int g = bid / NCHUNK;
    const int c = bid % NCHUNK;
    const int k0 = c * KT;

    // zero the OLA accumulator (seam quads need 0; interior overwritten anyway)
    if (tid < LOC_FLOATS / 4) {
        f32x4 z = {0.f, 0.f, 0.f, 0.f};
        *reinterpret_cast<f32x4*>(locout + 4 * tid) = z;
    }

    const float* eg = est + ((size_t)g * BCH) * KFR + k0;
    const float* mg = mix + ((size_t)g * NCH) * KFR + k0;

    // ---- GEMM1 m[n][f] = W[n][b] est[b][f], fused x = mix*relu(m) -> xt ----
#pragma unroll
    for (int ft = 0; ft < 2; ++ft) {
        const int f = 16 * ft + l15;
        const int sg = ((f >> 2) & 3) << 1;
        // B-fragments for this f-column, built directly from global est
        const float* ep = eg + (size_t)(8 * lq) * KFR + f;
        bf16x8 b0 = bfrag8(ep);
        bf16x8 b1 = bfrag8(ep + (size_t)32 * KFR);
        bf16x8 b2 = bfrag8(ep + (size_t)64 * KFR);
        bf16x8 b3 = bfrag8(ep + (size_t)96 * KFR);
#pragma unroll
        for (int nt = 0; nt < 4; ++nt) {
            const unsigned short* wr = wbf + (64 * wv + 16 * nt + l15) * BCH + 8 * lq;
            bf16x8 w0 = *reinterpret_cast<const bf16x8*>(wr);
            bf16x8 w1 = *reinterpret_cast<const bf16x8*>(wr + 32);
            bf16x8 w2 = *reinterpret_cast<const bf16x8*>(wr + 64);
            bf16x8 w3 = *reinterpret_cast<const bf16x8*>(wr + 96);
            f32x4 a = {0.f, 0.f, 0.f, 0.f};
            a = __builtin_amdgcn_mfma_f32_16x16x32_bf16(w0, b0, a, 0, 0, 0);
            a = __builtin_amdgcn_mfma_f32_16x16x32_bf16(w1, b1, a, 0, 0, 0);
            a = __builtin_amdgcn_mfma_f32_16x16x32_bf16(w2, b2, a, 0, 0, 0);
            a = __builtin_amdgcn_mfma_f32_16x16x32_bf16(w3, b3, a, 0, 0, 0);
            // epilogue: x = mix * relu(m); D rows n0..n0+3, col f
            f32x4 m = mload(mg + (size_t)(64 * wv + 16 * nt + 4 * lq) * KFR + f);
            float x0 = (a[0] > 0.f) ? m[0] * a[0] : 0.f;
            float x1 = (a[1] > 0.f) ? m[1] * a[1] : 0.f;
            float x2 = (a[2] > 0.f) ? m[2] * a[2] : 0.f;
            float x3 = (a[3] > 0.f) ? m[3] * a[3] : 0.f;
            int ue = 8 * wv + 2 * nt + (lq >> 1);
            uint2 uu;
            uu.x = pack2(x0, x1);
            uu.y = pack2(x2, x3);
            *reinterpret_cast<uint2*>(xtd + f * XTW + (((ue ^ sg) << 2) | (2 * (lq & 1)))) = uu;
        }
    }
    __syncthreads();   // xt + locout-zero ready

    // ---- GEMM2 y[l][f] = Wb[l][n] x[n][f] (waves 0-1); shuffle-OLA -> locout ----
    if (wv < 2) {
        const int f = 16 * wv + l15;
        const int sg = ((f >> 2) & 3) << 1;
        const unsigned int* br = xtd + f * XTW;
        const unsigned short* wb2 = wbf + NCH * BCH + l15 * NCH + 8 * lq;
        f32x4 acc2 = {0.f, 0.f, 0.f, 0.f};
#pragma unroll
        for (int ks = 0; ks < 8; ++ks) {
            bf16x8 a = *reinterpret_cast<const bf16x8*>(wb2 + 32 * ks);
            bf16x8 b = *reinterpret_cast<const bf16x8*>(br + (((4 * ks + lq) ^ sg) << 2));
            acc2 = __builtin_amdgcn_mfma_f32_16x16x32_bf16(a, b, acc2, 0, 0, 0);
        }
        // in-register overlap-add: lane (lq<2, l15) owns output quad [8f+4lq, +4)
        // = own louts 0-7 plus louts 8-15 of frame f-1 (held by lane+31)
        int src = (lane + 31) & 63;
        float p0 = __shfl(acc2[0], src, 64);
        float p1 = __shfl(acc2[1], src, 64);
        float p2 = __shfl(acc2[2], src, 64);
        float p3 = __shfl(acc2[3], src, 64);
        if (lq < 2) {
            int toff = 8 * f + 4 * lq;
            if (l15 == 0) {     // seam: partner is another wave/chunk
                atomicAdd(locout + toff + 0, acc2[0]);
                atomicAdd(locout + toff + 1, acc2[1]);
                atomicAdd(locout + toff + 2, acc2[2]);
                atomicAdd(locout + toff + 3, acc2[3]);
            } else {            // interior: both contributions in hand
                f32x4 s = {acc2[0] + p0, acc2[1] + p1, acc2[2] + p2, acc2[3] + p3};
                *reinterpret_cast<f32x4*>(locout + toff) = s;
            }
        } else if (l15 == 15) { // louts 8-15 of frame 16wv+15 -> next group's seam
            int toff = 8 * (16 * wv + 16) + 4 * (lq - 2);
            atomicAdd(locout + toff + 0, acc2[0]);
            atomicAdd(locout + toff + 1, acc2[1]);
            atomicAdd(locout + toff + 2, acc2[2]);
            atomicAdd(locout + toff + 3, acc2[3]);
        }
    }
    __syncthreads();   // locout complete

    // ---- final store: plain float4 interior, atomic 8-float chunk edges ----
    if (tid < LOC_FLOATS / 4) {
        float* og = out + (size_t)g * TOUT + (size_t)(8 * KT) * c;
        f32x4 v = *reinterpret_cast<const f32x4*>(locout + 4 * tid);
        if (tid >= 2 && tid < (LOC_FLOATS / 4 - 2)) {
            *reinterpret_cast<f32x4*>(og + 4 * tid) = v;
        } else {
            atomicAdd(og + 4 * tid + 0, v[0]);
            atomicAdd(og + 4 * tid + 1, v[1]);
            atomicAdd(og + 4 * tid + 2, v[2]);
            atomicAdd(og + 4 * tid + 3, v[3]);
        }
    }
}

extern "C" void kernel_launch(void* const* d_in, const int* in_sizes, int n_in,
                              void* d_out, int out_size, void* d_ws, size_t ws_size,
                              hipStream_t stream) {
    const float* mix = (const float*)d_in[0];   // [8][256][32000]
    const float* est = (const float*)d_in[1];   // [8][128][32000]
    const float* Wm  = (const float*)d_in[2];   // [256][128]
    const float* Wb  = (const float*)d_in[3];   // [16][256]
    unsigned short* wbf = (unsigned short*)d_ws;

    hipMemsetAsync(d_out, 0, (size_t)out_size * sizeof(float), stream);
    convert_weights<<<128, 256, 0, stream>>>(Wm, Wb, wbf);
    fused_decoder<<<BATCH * NCHUNK, 256, 0, stream>>>(mix, est, wbf, (float*)d_out);
}

// Round 10
// 256.756 us; speedup vs baseline: 1.9711x; 1.9711x over previous
//
#include <hip/hip_runtime.h>
#include <stdint.h>

#define BATCH 8
#define NCH 256
#define BCH 128
#define KFR 32000
#define TOUT 256008
#define KT 32                    // frames per block (one tile per block)
#define NCHUNK (KFR / KT)        // 1000
#define XTW 128                  // words per xt row (256 bf16 n-channels)
#define LOC_FLOATS (8 * KT + 8)  // 264

typedef __attribute__((ext_vector_type(8))) short bf16x8;
typedef __attribute__((ext_vector_type(4))) float f32x4;
typedef __attribute__((ext_vector_type(4))) unsigned int u32x4;

__device__ __forceinline__ unsigned short f32_to_bf16(float f) {
    unsigned int u = __builtin_bit_cast(unsigned int, f);
    u += 0x7FFFu + ((u >> 16) & 1u);   // round-to-nearest-even
    return (unsigned short)(u >> 16);
}
__device__ __forceinline__ unsigned int pack2(float a, float b) {
    return (unsigned int)f32_to_bf16(a) | ((unsigned int)f32_to_bf16(b) << 16);
}
// 4 strided scalar loads (stride KFR) into an ext_vector (SROA-safe)
__device__ __forceinline__ f32x4 mload(const float* p) {
    f32x4 v;
    v[0] = p[0];
    v[1] = p[(size_t)KFR];
    v[2] = p[(size_t)2 * KFR];
    v[3] = p[(size_t)3 * KFR];
    return v;
}
// MFMA B-fragment (8 consecutive b-rows at column f) straight from global fp32
__device__ __forceinline__ bf16x8 bfrag8(const float* p) {
    u32x4 t;
    t[0] = pack2(p[0],              p[(size_t)KFR]);
    t[1] = pack2(p[(size_t)2 * KFR], p[(size_t)3 * KFR]);
    t[2] = pack2(p[(size_t)4 * KFR], p[(size_t)5 * KFR]);
    t[3] = pack2(p[(size_t)6 * KFR], p[(size_t)7 * KFR]);
    return __builtin_bit_cast(bf16x8, t);
}

__global__ void convert_weights(const float* __restrict__ Wm,
                                const float* __restrict__ Wb,
                                unsigned short* __restrict__ wbf) {
    int i = blockIdx.x * 256 + threadIdx.x;
    if (i < NCH * BCH) wbf[i] = f32_to_bf16(Wm[i]);
    if (i < 16 * NCH)  wbf[NCH * BCH + i] = f32_to_bf16(Wb[i]);
}

__global__ __launch_bounds__(256, 4)
void fused_decoder(const float* __restrict__ mix,
                   const float* __restrict__ est,
                   const unsigned short* __restrict__ wbf,
                   float* __restrict__ out) {
    __shared__ __align__(16) unsigned int xtd[32 * XTW];   // x bf16 [32 f][256 n], swizzled
    __shared__ __align__(16) float locout[LOC_FLOATS];     // per-chunk OLA accumulator

    const int tid = threadIdx.x;
    const int lane = tid & 63;
    const int wv = tid >> 6;
    const int l15 = lane & 15;
    const int lq = lane >> 4;

    const int bid = blockIdx.x;
    const int g = bid / NCHUNK;
    const int c = bid % NCHUNK;
    const int k0 = c * KT;

    // zero the OLA accumulator (seam quads need 0; interior overwritten anyway)
    if (tid < LOC_FLOATS / 4) {
        f32x4 z = {0.f, 0.f, 0.f, 0.f};
        *reinterpret_cast<f32x4*>(locout + 4 * tid) = z;
    }

    const float* eg = est + ((size_t)g * BCH) * KFR + k0;
    const float* mg = mix + ((size_t)g * NCH) * KFR + k0;

    // ---- GEMM1 m[n][f] = W[n][b] est[b][f], fused x = mix*relu(m) -> xt ----
#pragma unroll
    for (int ft = 0; ft < 2; ++ft) {
        const int f = 16 * ft + l15;
        const int sg = ((f >> 2) & 3) << 1;
        // B-fragments for this f-column, built directly from global est
        const float* ep = eg + (size_t)(8 * lq) * KFR + f;
        bf16x8 b0 = bfrag8(ep);
        bf16x8 b1 = bfrag8(ep + (size_t)32 * KFR);
        bf16x8 b2 = bfrag8(ep + (size_t)64 * KFR);
        bf16x8 b3 = bfrag8(ep + (size_t)96 * KFR);
#pragma unroll
        for (int nt = 0; nt < 4; ++nt) {
            const unsigned short* wr = wbf + (64 * wv + 16 * nt + l15) * BCH + 8 * lq;
            bf16x8 w0 = *reinterpret_cast<const bf16x8*>(wr);
            bf16x8 w1 = *reinterpret_cast<const bf16x8*>(wr + 32);
            bf16x8 w2 = *reinterpret_cast<const bf16x8*>(wr + 64);
            bf16x8 w3 = *reinterpret_cast<const bf16x8*>(wr + 96);
            f32x4 a = {0.f, 0.f, 0.f, 0.f};
            a = __builtin_amdgcn_mfma_f32_16x16x32_bf16(w0, b0, a, 0, 0, 0);
            a = __builtin_amdgcn_mfma_f32_16x16x32_bf16(w1, b1, a, 0, 0, 0);
            a = __builtin_amdgcn_mfma_f32_16x16x32_bf16(w2, b2, a, 0, 0, 0);
            a = __builtin_amdgcn_mfma_f32_16x16x32_bf16(w3, b3, a, 0, 0, 0);
            // epilogue: x = mix * relu(m); D rows n0..n0+3, col f
            f32x4 m = mload(mg + (size_t)(64 * wv + 16 * nt + 4 * lq) * KFR + f);
            float x0 = (a[0] > 0.f) ? m[0] * a[0] : 0.f;
            float x1 = (a[1] > 0.f) ? m[1] * a[1] : 0.f;
            float x2 = (a[2] > 0.f) ? m[2] * a[2] : 0.f;
            float x3 = (a[3] > 0.f) ? m[3] * a[3] : 0.f;
            int ue = 8 * wv + 2 * nt + (lq >> 1);
            uint2 uu;
            uu.x = pack2(x0, x1);
            uu.y = pack2(x2, x3);
            *reinterpret_cast<uint2*>(xtd + f * XTW + (((ue ^ sg) << 2) | (2 * (lq & 1)))) = uu;
        }
    }
    __syncthreads();   // xt + locout-zero ready

    // ---- GEMM2 y[l][f] = Wb[l][n] x[n][f] (waves 0-1); shuffle-OLA -> locout ----
    if (wv < 2) {
        const int f = 16 * wv + l15;
        const int sg = ((f >> 2) & 3) << 1;
        const unsigned int* br = xtd + f * XTW;
        const unsigned short* wb2 = wbf + NCH * BCH + l15 * NCH + 8 * lq;
        f32x4 acc2 = {0.f, 0.f, 0.f, 0.f};
#pragma unroll
        for (int ks = 0; ks < 8; ++ks) {
            bf16x8 a = *reinterpret_cast<const bf16x8*>(wb2 + 32 * ks);
            bf16x8 b = *reinterpret_cast<const bf16x8*>(br + (((4 * ks + lq) ^ sg) << 2));
            acc2 = __builtin_amdgcn_mfma_f32_16x16x32_bf16(a, b, acc2, 0, 0, 0);
        }
        // in-register overlap-add: lane (lq<2, l15) owns output quad [8f+4lq, +4)
        // = own louts 0-7 plus louts 8-15 of frame f-1 (held by lane+31)
        int src = (lane + 31) & 63;
        float p0 = __shfl(acc2[0], src, 64);
        float p1 = __shfl(acc2[1], src, 64);
        float p2 = __shfl(acc2[2], src, 64);
        float p3 = __shfl(acc2[3], src, 64);
        if (lq < 2) {
            int toff = 8 * f + 4 * lq;
            if (l15 == 0) {     // seam: partner is another wave/chunk
                atomicAdd(locout + toff + 0, acc2[0]);
                atomicAdd(locout + toff + 1, acc2[1]);
                atomicAdd(locout + toff + 2, acc2[2]);
                atomicAdd(locout + toff + 3, acc2[3]);
            } else {            // interior: both contributions in hand
                f32x4 s = {acc2[0] + p0, acc2[1] + p1, acc2[2] + p2, acc2[3] + p3};
                *reinterpret_cast<f32x4*>(locout + toff) = s;
            }
        } else if (l15 == 15) { // louts 8-15 of frame 16wv+15 -> next group's seam
            int toff = 8 * (16 * wv + 16) + 4 * (lq - 2);
            atomicAdd(locout + toff + 0, acc2[0]);
            atomicAdd(locout + toff + 1, acc2[1]);
            atomicAdd(locout + toff + 2, acc2[2]);
            atomicAdd(locout + toff + 3, acc2[3]);
        }
    }
    __syncthreads();   // locout complete

    // ---- final store: plain float4 interior, atomic 8-float chunk edges ----
    if (tid < LOC_FLOATS / 4) {
        float* og = out + (size_t)g * TOUT + (size_t)(8 * KT) * c;
        f32x4 v = *reinterpret_cast<const f32x4*>(locout + 4 * tid);
        if (tid >= 2 && tid < (LOC_FLOATS / 4 - 2)) {
            *reinterpret_cast<f32x4*>(og + 4 * tid) = v;
        } else {
            atomicAdd(og + 4 * tid + 0, v[0]);
            atomicAdd(og + 4 * tid + 1, v[1]);
            atomicAdd(og + 4 * tid + 2, v[2]);
            atomicAdd(og + 4 * tid + 3, v[3]);
        }
    }
}

extern "C" void kernel_launch(void* const* d_in, const int* in_sizes, int n_in,
                              void* d_out, int out_size, void* d_ws, size_t ws_size,
                              hipStream_t stream) {
    const float* mix = (const float*)d_in[0];   // [8][256][32000]
    const float* est = (const float*)d_in[1];   // [8][128][32000]
    const float* Wm  = (const float*)d_in[2];   // [256][128]
    const float* Wb  = (const float*)d_in[3];   // [16][256]
    unsigned short* wbf = (unsigned short*)d_ws;

    hipMemsetAsync(d_out, 0, (size_t)out_size * sizeof(float), stream);
    convert_weights<<<128, 256, 0, stream>>>(Wm, Wb, wbf);
    fused_decoder<<<BATCH * NCHUNK, 256, 0, stream>>>(mix, est, wbf, (float*)d_out);
}

// Round 11
// 153.856 us; speedup vs baseline: 3.2893x; 1.6688x over previous
//
#include <hip/hip_runtime.h>
#include <stdint.h>

#define BATCH 8
#define NCH 256
#define BCH 128
#define KFR 32000
#define TOUT 256008
#define KT 32                    // frames per block (one tile per block)
#define NCHUNK (KFR / KT)        // 1000 -> grid 8000
#define ESTW 64                  // words per estd row (32 rows)
#define XTW 128                  // words per xtd row (32 rows)
#define LOC_FLOATS (8 * KT + 8)  // 264

typedef __attribute__((ext_vector_type(8))) short bf16x8;
typedef __attribute__((ext_vector_type(4))) float f32x4;

__device__ __forceinline__ unsigned short f32_to_bf16(float f) {
    unsigned int u = __builtin_bit_cast(unsigned int, f);
    u += 0x7FFFu + ((u >> 16) & 1u);   // round-to-nearest-even
    return (unsigned short)(u >> 16);
}
__device__ __forceinline__ unsigned int pack2(float a, float b) {
    return (unsigned int)f32_to_bf16(a) | ((unsigned int)f32_to_bf16(b) << 16);
}
// 16B-granular XOR swizzle used by est staging writes and GEMM1 A-frag reads
__device__ __forceinline__ int swz(int row, int w) {
    return (((w >> 2) ^ (((row >> 2) & 3) << 1)) << 2) | (w & 3);
}

__global__ void convert_weights(const float* __restrict__ Wm,
                                const float* __restrict__ Wb,
                                unsigned short* __restrict__ wbf) {
    int i = blockIdx.x * 256 + threadIdx.x;
    if (i < NCH * BCH) wbf[i] = f32_to_bf16(Wm[i]);
    if (i < 16 * NCH)  wbf[NCH * BCH + i] = f32_to_bf16(Wb[i]);
}

__global__ __launch_bounds__(256, 4)
void fused_decoder(const float* __restrict__ mix,
                   const float* __restrict__ est,
                   const unsigned short* __restrict__ wbf,
                   float* __restrict__ out) {
    __shared__ __align__(16) unsigned int estd[32 * ESTW];  // est^T bf16 [32 f][128 b], swizzled
    __shared__ __align__(16) unsigned int xtd[32 * XTW];    // x bf16 [32 f][256 n], swizzled
    __shared__ __align__(16) float locout[LOC_FLOATS];      // OLA accumulator

    const int tid = threadIdx.x;
    const int lane = tid & 63;
    const int wv = tid >> 6;
    const int l15 = lane & 15;
    const int lq = lane >> 4;
    const int f4 = tid & 7;          // staging frame-quad
    const int c0 = tid >> 3;         // staging b-pair base, 0..31

    const int bid = blockIdx.x;
    const int g = bid / NCHUNK;
    const int c = bid % NCHUNK;
    const int k0 = c * KT;

    // zero the OLA accumulator (seam quads need 0; interior overwritten)
    if (tid < LOC_FLOATS / 4) {
        f32x4 z = {0.f, 0.f, 0.f, 0.f};
        *reinterpret_cast<f32x4*>(locout + 4 * tid) = z;
    }

    const float* eg = est + ((size_t)g * BCH) * KFR + k0;
    const float* mg = mix + ((size_t)g * NCH) * KFR + k0;

    // ---- phase A: est tile -> LDS estd (transposed bf16, swizzled) ----
    {
        f32x4 e0 = *reinterpret_cast<const f32x4*>(eg + (size_t)(2 * c0) * KFR + 4 * f4);
        f32x4 e1 = *reinterpret_cast<const f32x4*>(eg + (size_t)(2 * c0 + 1) * KFR + 4 * f4);
        f32x4 e2 = *reinterpret_cast<const f32x4*>(eg + (size_t)(2 * c0 + 64) * KFR + 4 * f4);
        f32x4 e3 = *reinterpret_cast<const f32x4*>(eg + (size_t)(2 * c0 + 65) * KFR + 4 * f4);
#pragma unroll
        for (int i = 0; i < 4; ++i) {
            int row = 4 * f4 + i;
            estd[row * ESTW + swz(row, c0)]      = pack2(e0[i], e1[i]);
            estd[row * ESTW + swz(row, c0 + 32)] = pack2(e2[i], e3[i]);
        }
    }
    __syncthreads();   // estd + locout-zero ready

    // ---- phase B: GEMM1 (swapped operands: D rows=f, cols=n) + fused epilogue ----
    // m^T[f][n] = est^T[f][b] * W^T[b][n]; lane holds f = 16ft+4lq+r, n = 64wv+16nt+l15
    {
        unsigned short* xts = reinterpret_cast<unsigned short*>(xtd);
#pragma unroll
        for (int nt = 0; nt < 4; ++nt) {
            const int n = 64 * wv + 16 * nt + l15;
            const unsigned short* wr = wbf + n * BCH + 8 * lq;
            bf16x8 w0 = *reinterpret_cast<const bf16x8*>(wr);
            bf16x8 w1 = *reinterpret_cast<const bf16x8*>(wr + 32);
            bf16x8 w2 = *reinterpret_cast<const bf16x8*>(wr + 64);
            bf16x8 w3 = *reinterpret_cast<const bf16x8*>(wr + 96);
#pragma unroll
            for (int ft = 0; ft < 2; ++ft) {
                const int fA = 16 * ft + l15;                 // A-frag row (est frame)
                const int sgA = ((l15 >> 2) & 3) << 1;        // == ((fA>>2)&3)<<1
                const unsigned int* br = estd + fA * ESTW;
                bf16x8 a0 = *reinterpret_cast<const bf16x8*>(br + (((0  + lq) ^ sgA) << 2));
                bf16x8 a1 = *reinterpret_cast<const bf16x8*>(br + (((4  + lq) ^ sgA) << 2));
                bf16x8 a2 = *reinterpret_cast<const bf16x8*>(br + (((8  + lq) ^ sgA) << 2));
                bf16x8 a3 = *reinterpret_cast<const bf16x8*>(br + (((12 + lq) ^ sgA) << 2));
                f32x4 a = {0.f, 0.f, 0.f, 0.f};
                a = __builtin_amdgcn_mfma_f32_16x16x32_bf16(a0, w0, a, 0, 0, 0);
                a = __builtin_amdgcn_mfma_f32_16x16x32_bf16(a1, w1, a, 0, 0, 0);
                a = __builtin_amdgcn_mfma_f32_16x16x32_bf16(a2, w2, a, 0, 0, 0);
                a = __builtin_amdgcn_mfma_f32_16x16x32_bf16(a3, w3, a, 0, 0, 0);
                // epilogue: lane's 4 acc elems are f0..f0+3 at fixed n -> ONE float4 mix load
                const int f0 = 16 * ft + 4 * lq;
                f32x4 m = *reinterpret_cast<const f32x4*>(mg + (size_t)n * KFR + f0);
                float x0 = (a[0] > 0.f) ? m[0] * a[0] : 0.f;
                float x1 = (a[1] > 0.f) ? m[1] * a[1] : 0.f;
                float x2 = (a[2] > 0.f) ? m[2] * a[2] : 0.f;
                float x3 = (a[3] > 0.f) ? m[3] * a[3] : 0.f;
                // xt[f0+r][n] bf16, swizzle sg = lq<<1 (constant over r)
                const int swi = (((n >> 3) ^ (lq << 1)) << 2) | ((n >> 1) & 3);
                const int base = f0 * 256 + swi * 2 + (n & 1);
                xts[base]       = f32_to_bf16(x0);
                xts[base + 256] = f32_to_bf16(x1);
                xts[base + 512] = f32_to_bf16(x2);
                xts[base + 768] = f32_to_bf16(x3);
            }
        }
    }
    __syncthreads();   // xt ready

    // ---- phase D: GEMM2 y[l][f] = Wb[l][n] x[n][f] (waves 0-1); shuffle-OLA -> locout ----
    if (wv < 2) {
        const int f = 16 * wv + l15;
        const int sg = ((f >> 2) & 3) << 1;
        const unsigned int* br = xtd + f * XTW;
        const unsigned short* wb2 = wbf + NCH * BCH + l15 * NCH + 8 * lq;
        f32x4 acc2 = {0.f, 0.f, 0.f, 0.f};
#pragma unroll
        for (int ks = 0; ks < 8; ++ks) {
            bf16x8 a = *reinterpret_cast<const bf16x8*>(wb2 + 32 * ks);
            bf16x8 b = *reinterpret_cast<const bf16x8*>(br + (((4 * ks + lq) ^ sg) << 2));
            acc2 = __builtin_amdgcn_mfma_f32_16x16x32_bf16(a, b, acc2, 0, 0, 0);
        }
        // lane (lq<2, l15) owns output quad [8f+4lq, +4): own louts 0-7 plus
        // louts 8-15 of frame f-1 (held by lane+31)
        int src = (lane + 31) & 63;
        float p0 = __shfl(acc2[0], src, 64);
        float p1 = __shfl(acc2[1], src, 64);
        float p2 = __shfl(acc2[2], src, 64);
        float p3 = __shfl(acc2[3], src, 64);
        if (lq < 2) {
            int toff = 8 * f + 4 * lq;
            if (l15 == 0) {     // seam: partner is another wave/chunk
                atomicAdd(locout + toff + 0, acc2[0]);
                atomicAdd(locout + toff + 1, acc2[1]);
                atomicAdd(locout + toff + 2, acc2[2]);
                atomicAdd(locout + toff + 3, acc2[3]);
            } else {            // interior: both contributions in hand
                f32x4 s = {acc2[0] + p0, acc2[1] + p1, acc2[2] + p2, acc2[3] + p3};
                *reinterpret_cast<f32x4*>(locout + toff) = s;
            }
        } else if (l15 == 15) { // louts 8-15 of frame 16wv+15 -> next group's seam
            int toff = 8 * (16 * wv + 16) + 4 * (lq - 2);
            atomicAdd(locout + toff + 0, acc2[0]);
            atomicAdd(locout + toff + 1, acc2[1]);
            atomicAdd(locout + toff + 2, acc2[2]);
            atomicAdd(locout + toff + 3, acc2[3]);
        }
    }
    __syncthreads();   // locout complete

    // ---- final store: plain float4 interior, atomic 8-float chunk edges ----
    if (tid < LOC_FLOATS / 4) {
        float* og = out + (size_t)g * TOUT + (size_t)(8 * KT) * c;
        f32x4 v = *reinterpret_cast<const f32x4*>(locout + 4 * tid);
        if (tid >= 2 && tid < (LOC_FLOATS / 4 - 2)) {
            *reinterpret_cast<f32x4*>(og + 4 * tid) = v;
        } else {
            atomicAdd(og + 4 * tid + 0, v[0]);
            atomicAdd(og + 4 * tid + 1, v[1]);
            atomicAdd(og + 4 * tid + 2, v[2]);
            atomicAdd(og + 4 * tid + 3, v[3]);
        }
    }
}

extern "C" void kernel_launch(void* const* d_in, const int* in_sizes, int n_in,
                              void* d_out, int out_size, void* d_ws, size_t ws_size,
                              hipStream_t stream) {
    const float* mix = (const float*)d_in[0];   // [8][256][32000]
    const float* est = (const float*)d_in[1];   // [8][128][32000]
    const float* Wm  = (const float*)d_in[2];   // [256][128]
    const float* Wb  = (const float*)d_in[3];   // [16][256]
    unsigned short* wbf = (unsigned short*)d_ws;

    hipMemsetAsync(d_out, 0, (size_t)out_size * sizeof(float), stream);
    convert_weights<<<128, 256, 0, stream>>>(Wm, Wb, wbf);
    fused_decoder<<<BATCH * NCHUNK, 256, 0, stream>>>(mix, est, wbf, (float*)d_out);
}

// Round 12
// 144.550 us; speedup vs baseline: 3.5011x; 1.0644x over previous
//
#include <hip/hip_runtime.h>
#include <stdint.h>

#define BATCH 8
#define NCH 256
#define BCH 128
#define KFR 32000
#define TOUT 256008
#define KT 32                    // frames per block (one tile per block)
#define NCHUNK (KFR / KT)        // 1000 -> grid 8000
#define ESTW 68                  // words per estd row (64 data + 4 pad)
#define XTW 132                  // words per xtd row (128 data + 4 pad)
#define LOC_FLOATS (8 * KT + 8)  // 264

typedef __attribute__((ext_vector_type(8))) short bf16x8;
typedef __attribute__((ext_vector_type(4))) float f32x4;

__device__ __forceinline__ unsigned short f32_to_bf16(float f) {
    unsigned int u = __builtin_bit_cast(unsigned int, f);
    u += 0x7FFFu + ((u >> 16) & 1u);   // round-to-nearest-even
    return (unsigned short)(u >> 16);
}
__device__ __forceinline__ unsigned int pack2(float a, float b) {
    return (unsigned int)f32_to_bf16(a) | ((unsigned int)f32_to_bf16(b) << 16);
}
// 16B-granular XOR swizzle (same formula on write and read sides)
__device__ __forceinline__ int swz(int row, int w) {
    return (((w >> 2) ^ (((row >> 2) & 3) << 1)) << 2) | (w & 3);
}

__global__ void convert_weights(const float* __restrict__ Wm,
                                const float* __restrict__ Wb,
                                unsigned short* __restrict__ wbf) {
    int i = blockIdx.x * 256 + threadIdx.x;
    if (i < NCH * BCH) wbf[i] = f32_to_bf16(Wm[i]);
    if (i < 16 * NCH)  wbf[NCH * BCH + i] = f32_to_bf16(Wb[i]);
}

// one GEMM1 16x16 tile (nt,ft), swapped operands (D rows = f, cols = n),
// fused x = mix*relu(m) epilogue -> xt (bf16, swizzled, padded stride)
#define G1(NT, FT, MM) { \
    const int n = 64 * wv + 16 * (NT) + l15; \
    const unsigned short* wr = wbf + n * BCH + 8 * lq; \
    bf16x8 w0 = *reinterpret_cast<const bf16x8*>(wr); \
    bf16x8 w1 = *reinterpret_cast<const bf16x8*>(wr + 32); \
    bf16x8 w2 = *reinterpret_cast<const bf16x8*>(wr + 64); \
    bf16x8 w3 = *reinterpret_cast<const bf16x8*>(wr + 96); \
    const int fA = 16 * (FT) + l15; \
    const int sgA = ((l15 >> 2) & 3) << 1; \
    const unsigned int* br = estd + fA * ESTW; \
    bf16x8 a0 = *reinterpret_cast<const bf16x8*>(br + (((0  + lq) ^ sgA) << 2)); \
    bf16x8 a1 = *reinterpret_cast<const bf16x8*>(br + (((4  + lq) ^ sgA) << 2)); \
    bf16x8 a2 = *reinterpret_cast<const bf16x8*>(br + (((8  + lq) ^ sgA) << 2)); \
    bf16x8 a3 = *reinterpret_cast<const bf16x8*>(br + (((12 + lq) ^ sgA) << 2)); \
    f32x4 a = {0.f, 0.f, 0.f, 0.f}; \
    a = __builtin_amdgcn_mfma_f32_16x16x32_bf16(a0, w0, a, 0, 0, 0); \
    a = __builtin_amdgcn_mfma_f32_16x16x32_bf16(a1, w1, a, 0, 0, 0); \
    a = __builtin_amdgcn_mfma_f32_16x16x32_bf16(a2, w2, a, 0, 0, 0); \
    a = __builtin_amdgcn_mfma_f32_16x16x32_bf16(a3, w3, a, 0, 0, 0); \
    float x0 = (a[0] > 0.f) ? (MM)[0] * a[0] : 0.f; \
    float x1 = (a[1] > 0.f) ? (MM)[1] * a[1] : 0.f; \
    float x2 = (a[2] > 0.f) ? (MM)[2] * a[2] : 0.f; \
    float x3 = (a[3] > 0.f) ? (MM)[3] * a[3] : 0.f; \
    const int f0 = 16 * (FT) + 4 * lq; \
    const int swi = (((n >> 3) ^ (lq << 1)) << 2) | ((n >> 1) & 3); \
    const int base = f0 * (2 * XTW) + swi * 2 + (n & 1); \
    xts[base]               = f32_to_bf16(x0); \
    xts[base + 2 * XTW]     = f32_to_bf16(x1); \
    xts[base + 4 * XTW]     = f32_to_bf16(x2); \
    xts[base + 6 * XTW]     = f32_to_bf16(x3); \
}

__global__ __launch_bounds__(256, 2)
void fused_decoder(const float* __restrict__ mix,
                   const float* __restrict__ est,
                   const unsigned short* __restrict__ wbf,
                   float* __restrict__ out) {
    __shared__ __align__(16) unsigned int estd[32 * ESTW];  // est^T bf16, swizzled+padded
    __shared__ __align__(16) unsigned int xtd[32 * XTW];    // x bf16, swizzled+padded
    __shared__ __align__(16) float locout[LOC_FLOATS];      // OLA accumulator

    const int tid = threadIdx.x;
    const int lane = tid & 63;
    const int wv = tid >> 6;
    const int l15 = lane & 15;
    const int lq = lane >> 4;
    const int f4 = tid & 7;          // staging frame-quad
    const int c0 = tid >> 3;         // staging b-pair base, 0..31

    const int bid = blockIdx.x;
    const int g = bid / NCHUNK;
    const int c = bid % NCHUNK;
    const int k0 = c * KT;

    // zero the OLA accumulator (seam quads need 0; interior overwritten)
    if (tid < LOC_FLOATS / 4) {
        f32x4 z = {0.f, 0.f, 0.f, 0.f};
        *reinterpret_cast<f32x4*>(locout + 4 * tid) = z;
    }

    const float* eg = est + ((size_t)g * BCH) * KFR + k0;
    const float* mg = mix + ((size_t)g * NCH) * KFR + k0;

    // ---- issue ALL independent global loads up front (12 f32x4 in flight) ----
    f32x4 e0 = *reinterpret_cast<const f32x4*>(eg + (size_t)(2 * c0) * KFR + 4 * f4);
    f32x4 e1 = *reinterpret_cast<const f32x4*>(eg + (size_t)(2 * c0 + 1) * KFR + 4 * f4);
    f32x4 e2 = *reinterpret_cast<const f32x4*>(eg + (size_t)(2 * c0 + 64) * KFR + 4 * f4);
    f32x4 e3 = *reinterpret_cast<const f32x4*>(eg + (size_t)(2 * c0 + 65) * KFR + 4 * f4);
    const float* pmb = mg + (size_t)(64 * wv + l15) * KFR + 4 * lq;  // mix[n=64wv+16nt+l15][f0=16ft+4lq]
    f32x4 m00 = *reinterpret_cast<const f32x4*>(pmb);
    f32x4 m01 = *reinterpret_cast<const f32x4*>(pmb + 16);
    f32x4 m10 = *reinterpret_cast<const f32x4*>(pmb + (size_t)16 * KFR);
    f32x4 m11 = *reinterpret_cast<const f32x4*>(pmb + (size_t)16 * KFR + 16);
    f32x4 m20 = *reinterpret_cast<const f32x4*>(pmb + (size_t)32 * KFR);
    f32x4 m21 = *reinterpret_cast<const f32x4*>(pmb + (size_t)32 * KFR + 16);
    f32x4 m30 = *reinterpret_cast<const f32x4*>(pmb + (size_t)48 * KFR);
    f32x4 m31 = *reinterpret_cast<const f32x4*>(pmb + (size_t)48 * KFR + 16);

    // ---- phase A: est regs -> LDS estd (transposed bf16, swizzled) ----
#pragma unroll
    for (int i = 0; i < 4; ++i) {
        int row = 4 * f4 + i;
        estd[row * ESTW + swz(row, c0)]      = pack2(e0[i], e1[i]);
        estd[row * ESTW + swz(row, c0 + 32)] = pack2(e2[i], e3[i]);
    }
    __syncthreads();   // estd + locout-zero ready (mix loads drain here too)

    // ---- phase B: GEMM1 (swapped) + fused relu*mix epilogue -> xt ----
    {
        unsigned short* xts = reinterpret_cast<unsigned short*>(xtd);
        G1(0, 0, m00)
        G1(0, 1, m01)
        G1(1, 0, m10)
        G1(1, 1, m11)
        G1(2, 0, m20)
        G1(2, 1, m21)
        G1(3, 0, m30)
        G1(3, 1, m31)
    }
    __syncthreads();   // xt ready

    // ---- phase D: GEMM2 y[l][f] = Wb[l][n] x[n][f] (waves 0-1); shuffle-OLA -> locout ----
    if (wv < 2) {
        const int f = 16 * wv + l15;
        const int sg = ((f >> 2) & 3) << 1;
        const unsigned int* br = xtd + f * XTW;
        const unsigned short* wb2 = wbf + NCH * BCH + l15 * NCH + 8 * lq;
        f32x4 acc2 = {0.f, 0.f, 0.f, 0.f};
#pragma unroll
        for (int ks = 0; ks < 8; ++ks) {
            bf16x8 a = *reinterpret_cast<const bf16x8*>(wb2 + 32 * ks);
            bf16x8 b = *reinterpret_cast<const bf16x8*>(br + (((4 * ks + lq) ^ sg) << 2));
            acc2 = __builtin_amdgcn_mfma_f32_16x16x32_bf16(a, b, acc2, 0, 0, 0);
        }
        // lane (lq<2, l15) owns output quad [8f+4lq, +4): own louts 0-7 plus
        // louts 8-15 of frame f-1 (held by lane+31)
        int src = (lane + 31) & 63;
        float p0 = __shfl(acc2[0], src, 64);
        float p1 = __shfl(acc2[1], src, 64);
        float p2 = __shfl(acc2[2], src, 64);
        float p3 = __shfl(acc2[3], src, 64);
        if (lq < 2) {
            int toff = 8 * f + 4 * lq;
            if (l15 == 0) {     // seam: partner is another wave/chunk
                atomicAdd(locout + toff + 0, acc2[0]);
                atomicAdd(locout + toff + 1, acc2[1]);
                atomicAdd(locout + toff + 2, acc2[2]);
                atomicAdd(locout + toff + 3, acc2[3]);
            } else {            // interior: both contributions in hand
                f32x4 s = {acc2[0] + p0, acc2[1] + p1, acc2[2] + p2, acc2[3] + p3};
                *reinterpret_cast<f32x4*>(locout + toff) = s;
            }
        } else if (l15 == 15) { // louts 8-15 of frame 16wv+15 -> next group's seam
            int toff = 8 * (16 * wv + 16) + 4 * (lq - 2);
            atomicAdd(locout + toff + 0, acc2[0]);
            atomicAdd(locout + toff + 1, acc2[1]);
            atomicAdd(locout + toff + 2, acc2[2]);
            atomicAdd(locout + toff + 3, acc2[3]);
        }
    }
    __syncthreads();   // locout complete

    // ---- final store: plain float4 interior, atomic 8-float chunk edges ----
    if (tid < LOC_FLOATS / 4) {
        float* og = out + (size_t)g * TOUT + (size_t)(8 * KT) * c;
        f32x4 v = *reinterpret_cast<const f32x4*>(locout + 4 * tid);
        if (tid >= 2 && tid < (LOC_FLOATS / 4 - 2)) {
            *reinterpret_cast<f32x4*>(og + 4 * tid) = v;
        } else {
            atomicAdd(og + 4 * tid + 0, v[0]);
            atomicAdd(og + 4 * tid + 1, v[1]);
            atomicAdd(og + 4 * tid + 2, v[2]);
            atomicAdd(og + 4 * tid + 3, v[3]);
        }
    }
}

extern "C" void kernel_launch(void* const* d_in, const int* in_sizes, int n_in,
                              void* d_out, int out_size, void* d_ws, size_t ws_size,
                              hipStream_t stream) {
    const float* mix = (const float*)d_in[0];   // [8][256][32000]
    const float* est = (const float*)d_in[1];   // [8][128][32000]
    const float* Wm  = (const float*)d_in[2];   // [256][128]
    const float* Wb  = (const float*)d_in[3];   // [16][256]
    unsigned short* wbf = (unsigned short*)d_ws;

    hipMemsetAsync(d_out, 0, (size_t)out_size * sizeof(float), stream);
    convert_weights<<<128, 256, 0, stream>>>(Wm, Wb, wbf);
    fused_decoder<<<BATCH * NCHUNK, 256, 0, stream>>>(mix, est, wbf, (float*)d_out);
}